// Round 17
// baseline (200.745 us; speedup 1.0000x reference)
//
#include <hip/hip_runtime.h>

#define L_SEQ 2048
#define NH    16
#define E_DIM 1024
#define M_ROWS 4096

typedef unsigned short u16;
typedef unsigned int   u32;
typedef __attribute__((ext_vector_type(8))) __bf16 bf16x8;
typedef __attribute__((ext_vector_type(4))) float  f32x4;

__device__ __forceinline__ u16 f2bf(float f) {
  union { float f; u32 u; } x; x.f = f;
  u32 u = x.u;
  return (u16)((u + 0x7FFFu + ((u >> 16) & 1u)) >> 16);
}
__device__ __forceinline__ float bf2f(u16 v) {
  union { u32 u; float f; } x; x.u = ((u32)v) << 16;
  return x.f;
}
__device__ __forceinline__ void st_bf4(u16* p, float a, float b, float c, float d) {
  ushort4 u; u.x = f2bf(a); u.y = f2bf(b); u.z = f2bf(c); u.w = f2bf(d);
  *reinterpret_cast<ushort4*>(p) = u;
}
// async global->LDS, 16B per lane; LDS dest must be linear in lane order
__device__ __forceinline__ void gload16(const u16* g, u16* l) {
  __builtin_amdgcn_global_load_lds(
      (const __attribute__((address_space(1))) void*)g,
      (__attribute__((address_space(3))) void*)l, 16, 0, 0);
}
#define SBAR() asm volatile("s_barrier" ::: "memory")

// ---------------- fused prologue: 4x weight-transpose+gamma-fold | bias-fold | LN x-hat ----------------
// grid 8320: [0,4096) transpose, [4096,4224) bias_fold, [4224,8320) ln rows
__global__ __launch_bounds__(256) void prep_kernel(
    const float* __restrict__ tokens,
    const float* __restrict__ W0, const float* __restrict__ W1,
    const float* __restrict__ W2, const float* __restrict__ W3,
    const float* __restrict__ g0, const float* __restrict__ g1,
    const float* __restrict__ g2, const float* __restrict__ g3,
    const float* __restrict__ lb0, const float* __restrict__ lb1,
    const float* __restrict__ lb2, const float* __restrict__ lb3,
    const float* __restrict__ bs0, const float* __restrict__ bs1,
    const float* __restrict__ bs2, const float* __restrict__ bs3,
    u16* __restrict__ T0, u16* __restrict__ T1, u16* __restrict__ T2, u16* __restrict__ T3,
    float* __restrict__ bfold, u16* __restrict__ xhat)
{
  __shared__ __align__(16) float shm[32 * 33];
  const int bid = blockIdx.x;
  const int t = threadIdx.x;

  if (bid < 4096) {                                 // ---- transpose + gamma fold ----
    const int z = bid >> 10, rem = bid & 1023;
    const float* W = (z == 0) ? W0 : (z == 1) ? W1 : (z == 2) ? W2 : W3;
    const float* g = (z == 0) ? g0 : (z == 1) ? g1 : (z == 2) ? g2 : g3;
    u16* T = (z == 0) ? T0 : (z == 1) ? T1 : (z == 2) ? T2 : T3;
    float (*tile)[33] = (float(*)[33])shm;
    const int tx = t & 31, ty = t >> 5;
    const int bx = (rem & 31) * 32, by = (rem >> 5) * 32;
    #pragma unroll
    for (int r = 0; r < 4; ++r) {
      const int e = by + ty + r * 8;
      tile[ty + r * 8][tx] = W[(size_t)e * E_DIM + bx + tx] * g[e];
    }
    __syncthreads();
    #pragma unroll
    for (int r = 0; r < 4; ++r)
      T[(size_t)(bx + ty + r * 8) * E_DIM + by + tx] = f2bf(tile[tx][ty + r * 8]);
  } else if (bid < 4224) {                          // ---- bias fold ----
    const int idx = bid - 4096;
    const int z = idx >> 5;
    const float* W  = (z == 0) ? W0 : (z == 1) ? W1 : (z == 2) ? W2 : W3;
    const float* bl = (z == 0) ? lb0 : (z == 1) ? lb1 : (z == 2) ? lb2 : lb3;
    const float* bs = (z == 0) ? bs0 : (z == 1) ? bs1 : (z == 2) ? bs2 : bs3;
    float (*part)[32] = (float(*)[32])shm;
    const int tn = t & 31, te = t >> 5;
    const int n = (idx & 31) * 32 + tn;
    float acc = 0.f;
    const int e0 = te * 128;
    for (int e = e0; e < e0 + 128; ++e) acc += bl[e] * W[(size_t)e * E_DIM + n];
    part[te][tn] = acc;
    __syncthreads();
    if (te == 0) {
      float s = part[0][tn] + part[1][tn] + part[2][tn] + part[3][tn]
              + part[4][tn] + part[5][tn] + part[6][tn] + part[7][tn];
      bfold[z * E_DIM + n] = bs[n] + s;
    }
  } else {                                          // ---- LN x-hat (fp32 in -> bf16 out) ----
    float* red = shm;
    const size_t row = bid - 4224;
    float4 v = reinterpret_cast<const float4*>(tokens + row * E_DIM)[t];
    float s = v.x + v.y + v.z + v.w;
    float q = v.x*v.x + v.y*v.y + v.z*v.z + v.w*v.w;
    #pragma unroll
    for (int off = 32; off; off >>= 1) { s += __shfl_down(s, off); q += __shfl_down(q, off); }
    if ((t & 63) == 0) { red[t >> 6] = s; red[4 + (t >> 6)] = q; }
    __syncthreads();
    float S = red[0] + red[1] + red[2] + red[3];
    float Q = red[4] + red[5] + red[6] + red[7];
    float mean = S * (1.f / E_DIM);
    float rstd = rsqrtf(Q * (1.f / E_DIM) - mean * mean + 1e-5f);
    st_bf4(xhat + row * E_DIM + t * 4,
           (v.x - mean) * rstd, (v.y - mean) * rstd, (v.z - mean) * rstd, (v.w - mean) * rstd);
  }
}

// ---------------- combine(A-tile partials) + LayerNorm x-hat, one row per block ----------------
// Rows with qt>=16 come from po/pml partials (combined inline); qt<=15 rows read wvb.
__global__ __launch_bounds__(256) void ln_combine_hat(
    const u16* __restrict__ wvb, const float* __restrict__ po,
    const float* __restrict__ pml, u16* __restrict__ what)
{
  __shared__ float red[8];
  const int row = blockIdx.x;                       // b*L_SEQ + l
  const int t = threadIdx.x;
  const int l = row & (L_SEQ - 1), b = row >> 11;
  const int qt = l >> 6;
  float v0, v1, v2, v3;
  if (qt >= 16) {
    const int pr = 31 - qt;
    const int c = t * 4;
    const int h = c >> 6, d0 = c & 63;
    const int bh = b * NH + h;
    const int base = (bh * 16 + pr) * 2;
    const int rr = l & 63;
    const float m0 = pml[(size_t)base * 128 + rr];
    const float s0 = pml[(size_t)base * 128 + 64 + rr];
    const float m1 = pml[(size_t)(base + 1) * 128 + rr];
    const float s1 = pml[(size_t)(base + 1) * 128 + 64 + rr];
    const float mm = fmaxf(m0, m1);
    const float a0 = __expf(m0 - mm), a1 = __expf(m1 - mm);
    const float inv = 1.f / (s0 * a0 + s1 * a1);
    float4 x0 = *reinterpret_cast<const float4*>(po + ((size_t)base * 64 + rr) * 64 + d0);
    float4 x1 = *reinterpret_cast<const float4*>(po + ((size_t)(base + 1) * 64 + rr) * 64 + d0);
    v0 = (x0.x * a0 + x1.x * a1) * inv;
    v1 = (x0.y * a0 + x1.y * a1) * inv;
    v2 = (x0.z * a0 + x1.z * a1) * inv;
    v3 = (x0.w * a0 + x1.w * a1) * inv;
  } else {
    ushort4 u = reinterpret_cast<const ushort4*>(wvb + (size_t)row * E_DIM)[t];
    v0 = bf2f(u.x); v1 = bf2f(u.y); v2 = bf2f(u.z); v3 = bf2f(u.w);
  }
  float s = v0 + v1 + v2 + v3;
  float q = v0*v0 + v1*v1 + v2*v2 + v3*v3;
  #pragma unroll
  for (int off = 32; off; off >>= 1) { s += __shfl_down(s, off); q += __shfl_down(q, off); }
  if ((t & 63) == 0) { red[t >> 6] = s; red[4 + (t >> 6)] = q; }
  __syncthreads();
  float S = red[0] + red[1] + red[2] + red[3];
  float Q = red[4] + red[5] + red[6] + red[7];
  float mean = S * (1.f / E_DIM);
  float rstd = rsqrtf(Q * (1.f / E_DIM) - mean * mean + 1e-5f);
  st_bf4(what + (size_t)row * E_DIM + t * 4,
         (v0 - mean) * rstd, (v1 - mean) * rstd, (v2 - mean) * rstd, (v3 - mean) * rstd);
}

// ---------------- 128x128 counted-vmcnt GEMM core, BK=64, 4 waves, 64 KB LDS (R8-proven) ----------------
#define GBK 64
__device__ __forceinline__ void core128(
    const u16* __restrict__ A, const u16* __restrict__ BT,
    int m0, int n0, int t, u16* lds, f32x4 (&acc)[4][4])
{
  const int lane = t & 63, wave = t >> 6;
  const int wm = wave >> 1, wn = wave & 1;
  const int fr = lane & 15, hi = lane >> 4;
  const int sx = fr & 7;

  auto STAGE = [&](int buf, int kt) {
    u16* la = lds + (buf * 2 + 0) * (128 * GBK);
    u16* lb = lds + (buf * 2 + 1) * (128 * GBK);
    #pragma unroll
    for (int s = 0; s < 4; ++s) {
      const int seg = t + s * 256;
      const int r = seg >> 3;
      const int gc = (seg & 7) ^ (r & 7);            // inverse-swizzled source chunk
      gload16(A + (size_t)(m0 + r) * E_DIM + kt * GBK + gc * 8, la + seg * 8);
    }
    #pragma unroll
    for (int s = 0; s < 4; ++s) {
      const int seg = t + s * 256;
      const int r = seg >> 3;
      const int gc = (seg & 7) ^ (r & 7);
      gload16(BT + (size_t)(n0 + r) * E_DIM + kt * GBK + gc * 8, lb + seg * 8);
    }
  };
  auto AF = [&](int buf, int i, int ks) -> bf16x8 {
    return *reinterpret_cast<const bf16x8*>(
        lds + (buf * 2 + 0) * (128 * GBK) + (wm * 64 + i * 16 + fr) * GBK + (((ks * 4 + hi) ^ sx) * 8));
  };
  auto BF = [&](int buf, int j, int ks) -> bf16x8 {
    return *reinterpret_cast<const bf16x8*>(
        lds + (buf * 2 + 1) * (128 * GBK) + (wn * 64 + j * 16 + fr) * GBK + (((ks * 4 + hi) ^ sx) * 8));
  };
  auto PHASES = [&](int buf) {
    bf16x8 a[4][2], b[4][2];
    #pragma unroll
    for (int i = 0; i < 4; ++i) { a[i][0] = AF(buf, i, 0); a[i][1] = AF(buf, i, 1); }
    #pragma unroll
    for (int j = 0; j < 4; ++j) { b[j][0] = BF(buf, j, 0); b[j][1] = BF(buf, j, 1); }
    __builtin_amdgcn_s_setprio(1);
    #pragma unroll
    for (int i = 0; i < 4; ++i)
      #pragma unroll
      for (int j = 0; j < 4; ++j) {
        acc[i][j] = __builtin_amdgcn_mfma_f32_16x16x32_bf16(a[i][0], b[j][0], acc[i][j], 0, 0, 0);
        acc[i][j] = __builtin_amdgcn_mfma_f32_16x16x32_bf16(a[i][1], b[j][1], acc[i][j], 0, 0, 0);
      }
    __builtin_amdgcn_s_setprio(0);
  };

  STAGE(0, 0);                                      // prologue: kt0's 8 loads in flight
  #pragma unroll 1
  for (int kt = 0; kt < 15; ++kt) {
    const int buf = kt & 1;
    SBAR();                                         // all waves done reading buf^1 (kt-1)
    STAGE(buf ^ 1, kt + 1);                         // kt+1's 8 loads: stay in flight
    asm volatile("s_waitcnt vmcnt(8)" ::: "memory");// own kt loads done
    SBAR();                                         // => ALL waves' kt loads landed
    PHASES(buf);
  }
  asm volatile("s_waitcnt vmcnt(0)" ::: "memory");  // peeled last K-tile (kt=15, buf=1)
  SBAR();
  PHASES(1);
}

// ---------------- fused QKV GEMM: 768 blocks (32m x 24n), z = n0>>10 ----------------
// XCD-rectangle mapping (8m x 12n per XCD). Epilogue: scattered column-major stores
// (z=1 kout fp32, z=2 vTb bf16) go through an LDS transpose -> coalesced runs along L.
__global__ __launch_bounds__(256, 2) void gemm_qkv128(
    const u16* __restrict__ xhat, const u16* __restrict__ WTcat,
    const float* __restrict__ bfold,
    float* __restrict__ kout, float* __restrict__ vout,
    u16* __restrict__ qbf, u16* __restrict__ kbf, u16* __restrict__ vTb)
{
  __shared__ __align__(16) char smraw[128 * 132 * 4];   // 67.5 KB: core (64KB) / f32 xp[128][132] / u32 vp[128][68]
  u16* lds = (u16*)smraw;
  const int t = threadIdx.x;
  const int xcd = blockIdx.x & 7, l = blockIdx.x >> 3;  // l in [0,96)
  const int by = 8 * (xcd >> 1) + l / 12;
  const int bx = 12 * (xcd & 1) + l % 12;
  const int m0 = by * 128, n0 = bx * 128;

  f32x4 acc[4][4] = {};
  core128(xhat, WTcat, m0, n0, t, lds, acc);

  const int lane = t & 63, wave = t >> 6;
  const int wm = wave >> 1, wn = wave & 1;
  const int fr = lane & 15, hi = lane >> 4;
  const int z = n0 >> 10;
  const float* bias = bfold + z * E_DIM;
  const int rowb = hi * 4;
  const int bb = m0 >> 11;                              // batch (tile never crosses)

  if (z == 0) {
    #pragma unroll
    for (int i = 0; i < 4; ++i) {
      const int mbase = m0 + wm * 64 + i * 16 + rowb;
      #pragma unroll
      for (int j = 0; j < 4; ++j) {
        const int ncol = (n0 + wn * 64 + j * 16 + fr) & 1023;
        const float bval = bias[ncol];
        const int h = ncol >> 6, d = ncol & 63;
        #pragma unroll
        for (int r = 0; r < 4; ++r) {
          const int m = mbase + r;
          const int ltok = m & 2047;
          qbf[(((size_t)(bb * NH + h) * L_SEQ + ltok) << 6) + d] = f2bf(acc[i][j][r] + bval);
        }
      }
    }
  } else if (z == 1) {
    // kbf (row-major) direct; kout (fp32 column-major) via LDS transpose
    __syncthreads();                                    // core done with lds
    float (*xp)[132] = (float(*)[132])smraw;
    #pragma unroll
    for (int i = 0; i < 4; ++i) {
      const int mbase = m0 + wm * 64 + i * 16 + rowb;
      const int mloc = wm * 64 + i * 16 + rowb;
      #pragma unroll
      for (int j = 0; j < 4; ++j) {
        const int nl = wn * 64 + j * 16 + fr;
        const int ncol = (n0 + nl) & 1023;
        const float bval = bias[ncol];
        const int h = ncol >> 6, d = ncol & 63;
        #pragma unroll
        for (int r = 0; r < 4; ++r) {
          const int m = mbase + r;
          const int ltok = m & 2047;
          const float val = acc[i][j][r] + bval;
          kbf[(((size_t)(bb * NH + h) * L_SEQ + ltok) << 6) + d] = f2bf(val);
          xp[nl][mloc + r] = val;
        }
      }
    }
    __syncthreads();
    const int nl = t >> 1, mh = (t & 1) * 64;
    const int ncol2 = (n0 + nl) & 1023;
    const int h2 = ncol2 >> 6, d2 = ncol2 & 63;
    float4* dst = (float4*)(kout + ((size_t)(bb * NH + h2) * 64 + d2) * L_SEQ + (m0 & 2047) + mh);
    #pragma unroll
    for (int u = 0; u < 16; ++u)
      dst[u] = *reinterpret_cast<float4*>(&xp[nl][mh + u * 4]);
  } else {
    // vout (row-major-ish) direct; vTb (bf16 column-major) via LDS transpose (u32-packed)
    __syncthreads();
    u32 (*vp)[68] = (u32(*)[68])smraw;
    #pragma unroll
    for (int i = 0; i < 4; ++i) {
      const int mbase = m0 + wm * 64 + i * 16 + rowb;
      const int mloc = wm * 64 + i * 16 + rowb;
      #pragma unroll
      for (int j = 0; j < 4; ++j) {
        const int nl = wn * 64 + j * 16 + fr;
        const int ncol = (n0 + nl) & 1023;
        const float bval = bias[ncol];
        const int h = ncol >> 6, d = ncol & 63;
        float v4[4];
        #pragma unroll
        for (int r = 0; r < 4; ++r) {
          const int m = mbase + r;
          const int ltok = m & 2047;
          v4[r] = acc[i][j][r] + bval;
          vout[((size_t)(bb * NH + h) * L_SEQ + ltok) * 64 + d] = v4[r];
        }
        vp[nl][(mloc >> 1) + 0] = (u32)f2bf(v4[0]) | ((u32)f2bf(v4[1]) << 16);
        vp[nl][(mloc >> 1) + 1] = (u32)f2bf(v4[2]) | ((u32)f2bf(v4[3]) << 16);
      }
    }
    __syncthreads();
    const int nl = t >> 1, mh = (t & 1) * 64;
    const int ncol2 = (n0 + nl) & 1023;
    const int h2 = ncol2 >> 6, d2 = ncol2 & 63;
    uint4* dst = (uint4*)(vTb + ((size_t)(bb * NH + h2) * 64 + d2) * L_SEQ + (m0 & 2047) + mh);
    #pragma unroll
    for (int u = 0; u < 8; ++u)
      dst[u] = *reinterpret_cast<uint4*>(&vp[nl][(mh >> 1) + u * 4]);
  }
}

// ---------------- final GEMM: out = what @ (g_o . Wo) + bfold_o + tokens; 256 blocks ----------------
__global__ __launch_bounds__(256, 2) void gemm_o128(
    const u16* __restrict__ A, const u16* __restrict__ BT, const float* __restrict__ bias,
    const float* __restrict__ tokens, float* __restrict__ out)
{
  __shared__ u16 lds[4 * 128 * GBK];
  const int t = threadIdx.x;
  const int xcd = blockIdx.x & 7, l = blockIdx.x >> 3;  // l in [0,32)
  const int by = 8 * (xcd >> 1) + (l >> 2);
  const int bx = 4 * (xcd & 1) + (l & 3);
  const int m0 = by * 128, n0 = bx * 128;

  f32x4 acc[4][4] = {};
  core128(A, BT, m0, n0, t, lds, acc);

  const int lane = t & 63, wave = t >> 6;
  const int wm = wave >> 1, wn = wave & 1;
  const int fr = lane & 15, hi = lane >> 4;
  const int rowb = hi * 4;
  #pragma unroll
  for (int i = 0; i < 4; ++i) {
    const int mbase = m0 + wm * 64 + i * 16 + rowb;
    #pragma unroll
    for (int j = 0; j < 4; ++j) {
      const int ncol = n0 + wn * 64 + j * 16 + fr;
      const float bval = bias[ncol];
      #pragma unroll
      for (int r = 0; r < 4; ++r) {
        const int m = mbase + r;
        out[(size_t)m * E_DIM + ncol] = acc[i][j][r] + bval + tokens[(size_t)m * E_DIM + ncol];
      }
    }
  }
}

// ---------------- MFMA flash attention, SPLIT-PAIR + DIRECT K/V fragment loads ----------------
// K/V are L2-resident (512 KB per bh, XCD-grouped) -> no LDS staging, no block barriers
// (m169 lesson). Each lane loads its fragment 16B directly from kbf/vTb — bit-identical
// data to the old Klds/Vlds reads. Only per-wave Plds remains (9 KB LDS).
__global__ __launch_bounds__(256, 4) void attn_direct(
    const u16* __restrict__ qbf, const u16* __restrict__ kbf,
    const u16* __restrict__ vTb, u16* __restrict__ wv,
    float* __restrict__ po, float* __restrict__ pml)
{
  __shared__ u16 Plds[4][16][72];
  const int t = threadIdx.x, lane = t & 63, wave = t >> 6;
  const int bi = blockIdx.x;
  const int bh = (bi & 7) + 8 * ((bi >> 3) & 3);   // b*NH + h, XCD-grouped
  const int pp = bi >> 5;                          // 0..31
  const int half = pp & 1, pr = pp >> 1;           // pair 0..15
  const int fr = lane & 15, hi = lane >> 4;
  const int b = bh >> 4, h = bh & 15;
  const int qtA = 31 - pr, qtB = pr;
  // per-lane fragment base pointers (add (j0 + kt*16)*64 for K; dt*16*L + j0 for V)
  const u16* kfrag = kbf + (size_t)bh * L_SEQ * 64 + (size_t)fr * 64 + hi * 8;
  const u16* vfrag = vTb + (size_t)bh * 64 * L_SEQ + (size_t)fr * L_SEQ + hi * 8;

  auto TILE = [&](const bf16x8& qf0, const bf16x8& qf1, int qg, bool diag, int j0,
                  f32x4 (&o)[4], float& mrun, float& lrun) {
    f32x4 st[4] = {};
    __builtin_amdgcn_s_setprio(1);
    #pragma unroll
    for (int kt = 0; kt < 4; ++kt) {
      const u16* kp = kfrag + (size_t)(j0 + kt * 16) * 64;
      bf16x8 ka0 = *reinterpret_cast<const bf16x8*>(kp);
      bf16x8 ka1 = *reinterpret_cast<const bf16x8*>(kp + 32);
      st[kt] = __builtin_amdgcn_mfma_f32_16x16x32_bf16(ka0, qf0, st[kt], 0, 0, 0);
      st[kt] = __builtin_amdgcn_mfma_f32_16x16x32_bf16(ka1, qf1, st[kt], 0, 0, 0);
    }
    __builtin_amdgcn_s_setprio(0);

    float p[16];
    float pmax = -3.0e38f;
    #pragma unroll
    for (int kt = 0; kt < 4; ++kt)
      #pragma unroll
      for (int r = 0; r < 4; ++r) {
        const int key = j0 + kt*16 + hi*4 + r;
        const float v = st[kt][r] * 0.125f + ((diag && key > qg) ? -1249.875f : 0.f);
        p[kt*4 + r] = v;
        pmax = fmaxf(pmax, v);
      }
    pmax = fmaxf(pmax, __shfl_xor(pmax, 16));
    pmax = fmaxf(pmax, __shfl_xor(pmax, 32));
    const float mnew = fmaxf(mrun, pmax);
    const float alpha = __expf(mrun - mnew);
    float lsum = 0.f;
    #pragma unroll
    for (int i = 0; i < 16; ++i) { p[i] = __expf(p[i] - mnew); lsum += p[i]; }
    lsum += __shfl_xor(lsum, 16);
    lsum += __shfl_xor(lsum, 32);
    lrun = lrun * alpha + lsum;
    mrun = mnew;
    #pragma unroll
    for (int r = 0; r < 4; ++r) {
      const float ar = __shfl(alpha, hi*4 + r);
      o[0][r] *= ar; o[1][r] *= ar; o[2][r] *= ar; o[3][r] *= ar;
    }
    #pragma unroll
    for (int kt = 0; kt < 4; ++kt) {
      ushort4 w4;
      w4.x = f2bf(p[kt*4+0]); w4.y = f2bf(p[kt*4+1]);
      w4.z = f2bf(p[kt*4+2]); w4.w = f2bf(p[kt*4+3]);
      *reinterpret_cast<ushort4*>(&Plds[wave][fr][kt*16 + hi*4]) = w4;
    }
    const bf16x8 pf0 = *reinterpret_cast<const bf16x8*>(&Plds[wave][fr][hi*8]);
    const bf16x8 pf1 = *reinterpret_cast<const bf16x8*>(&Plds[wave][fr][32 + hi*8]);
    __builtin_amdgcn_s_setprio(1);
    #pragma unroll
    for (int dt = 0; dt < 4; ++dt) {
      const u16* vp = vfrag + (size_t)(dt * 16) * L_SEQ + j0;
      bf16x8 vf0 = *reinterpret_cast<const bf16x8*>(vp);
      bf16x8 vf1 = *reinterpret_cast<const bf16x8*>(vp + 32);
      o[dt] = __builtin_amdgcn_mfma_f32_16x16x32_bf16(pf0, vf0, o[dt], 0, 0, 0);
      o[dt] = __builtin_amdgcn_mfma_f32_16x16x32_bf16(pf1, vf1, o[dt], 0, 0, 0);
    }
    __builtin_amdgcn_s_setprio(0);
  };

  // ---- tile A segment ----
  {
    const int q0w = qtA * 64 + wave * 16;
    const int qg = q0w + fr;
    const u16* qrow = qbf + ((size_t)bh * L_SEQ + q0w + fr) * 64 + hi * 8;
    const bf16x8 qf0 = *reinterpret_cast<const bf16x8*>(qrow);
    const bf16x8 qf1 = *reinterpret_cast<const bf16x8*>(qrow + 32);
    f32x4 o[4] = {};
    float mrun = -3.0e38f, lrun = 0.f;
    const int lo = half ? 17 : 0;
    const int hiT = half ? qtA : 16;               // qtA >= 16 always; empty when half=1 && pr=15
    #pragma unroll 1
    for (int tkv = lo; tkv <= hiT; ++tkv)
      TILE(qf0, qf1, qg, tkv == qtA, tkv * 64, o, mrun, lrun);
    const int slot = (bh * 16 + pr) * 2 + half;
    float* pob = po + (size_t)slot * 4096;
    #pragma unroll
    for (int dt = 0; dt < 4; ++dt)
      #pragma unroll
      for (int r = 0; r < 4; ++r)
        pob[(wave * 16 + hi * 4 + r) * 64 + dt * 16 + fr] = o[dt][r];
    if (hi == 0) {
      pml[slot * 128 + wave * 16 + fr] = mrun;
      pml[slot * 128 + 64 + wave * 16 + fr] = lrun;
    }
  }

  // ---- tile B (half1 only, full range, written directly) ----
  if (half) {
    const int q0w = qtB * 64 + wave * 16;
    const int qg = q0w + fr;
    const u16* qrow = qbf + ((size_t)bh * L_SEQ + q0w + fr) * 64 + hi * 8;
    const bf16x8 qf0 = *reinterpret_cast<const bf16x8*>(qrow);
    const bf16x8 qf1 = *reinterpret_cast<const bf16x8*>(qrow + 32);
    f32x4 o[4] = {};
    float mrun = -3.0e38f, lrun = 0.f;
    #pragma unroll 1
    for (int tkv = 0; tkv <= qtB; ++tkv)
      TILE(qf0, qf1, qg, tkv == qtB, tkv * 64, o, mrun, lrun);
    const float inv = 1.f / lrun;
    #pragma unroll
    for (int r = 0; r < 4; ++r) {
      const float ir = __shfl(inv, hi * 4 + r);
      const int q = q0w + hi * 4 + r;
      u16* dst = wv + (size_t)(b * L_SEQ + q) * E_DIM + h * 64 + fr;
      #pragma unroll
      for (int dt = 0; dt < 4; ++dt)
        dst[dt * 16] = f2bf(o[dt][r] * ir);
    }
  }
}

extern "C" void kernel_launch(void* const* d_in, const int* in_sizes, int n_in,
                              void* d_out, int out_size, void* d_ws, size_t ws_size,
                              hipStream_t stream) {
  (void)in_sizes; (void)n_in; (void)out_size; (void)ws_size;
  const float* tokens = (const float*)d_in[0];
  const float* ln_q_g = (const float*)d_in[1];
  const float* ln_q_b = (const float*)d_in[2];
  const float* Wq     = (const float*)d_in[3];
  const float* bq     = (const float*)d_in[4];
  const float* ln_k_g = (const float*)d_in[5];
  const float* ln_k_b = (const float*)d_in[6];
  const float* Wk     = (const float*)d_in[7];
  const float* bk     = (const float*)d_in[8];
  const float* ln_v_g = (const float*)d_in[9];
  const float* ln_v_b = (const float*)d_in[10];
  const float* Wv     = (const float*)d_in[11];
  const float* bv     = (const float*)d_in[12];
  const float* ln_o_g = (const float*)d_in[13];
  const float* ln_o_b = (const float*)d_in[14];
  const float* Wo     = (const float*)d_in[15];
  const float* bo     = (const float*)d_in[16];

  float* out  = (float*)d_out;            // (2,2048,1024)
  float* kout = out + 4194304;            // (2,16,64,2048)
  float* vout = kout + 4194304;           // (2,16,2048,64)

  char* w = (char*)d_ws;
  const size_t MB = (size_t)1 << 20;
  u16*   WTq   = (u16*)(w + 0 * MB);     // (g_q . Wq)^T — WTq/WTv/WTk contiguous = WTcat (3072 x 1024)
  u16*   WTv   = (u16*)(w + 2 * MB);
  u16*   WTk   = (u16*)(w + 4 * MB);
  u16*   WTo   = (u16*)(w + 6 * MB);     // (g_o . Wo)^T
  u16*   xhat  = (u16*)(w + 8 * MB);     // shared LN x-hat; REUSED as wvb after gemm_qkv
  u16*   qbf   = (u16*)(w + 16 * MB);    // q bf16 (N,H,L,64)
  u16*   kbf   = (u16*)(w + 24 * MB);    // k bf16 (N,H,L,64)
  u16*   vTb   = (u16*)(w + 32 * MB);    // v^T bf16 (N,H,64,L)
  u16*   what  = (u16*)(w + 40 * MB);    // LN x-hat of wv
  float* bfold = (float*)(w + 48 * MB);  // 4 x 1024 folded biases (q, k(Wv), v(Wk), o)
  float* po    = (float*)(w + 49 * MB);  // tile-A partial o: 1024 x 64 x 64 f32 (16 MB)
  float* pml   = (float*)(w + 65 * MB);  // tile-A partial m,l: 1024 x 128 f32 (512 KB)
  u16*   wvb   = xhat;                   // attn out (N,L,E) — xhat dead after gemm_qkv

  prep_kernel<<<8320, 256, 0, stream>>>(
      tokens,
      Wq, Wv, Wk, Wo,
      ln_q_g, ln_v_g, ln_k_g, ln_o_g,
      ln_q_b, ln_v_b, ln_k_b, ln_o_b,
      bq, bv, bk, bo,
      WTq, WTv, WTk, WTo, bfold, xhat);
  gemm_qkv128<<<768, 256, 0, stream>>>(xhat, WTq, bfold, kout, vout, qbf, kbf, vTb);
  attn_direct<<<1024, 256, 0, stream>>>(qbf, kbf, vTb, wvb, po, pml);
  ln_combine_hat<<<M_ROWS, 256, 0, stream>>>(wvb, po, pml, what);
  gemm_o128<<<256, 256, 0, stream>>>(what, WTo, bfold + 3 * E_DIM, tokens, out);
}

// Round 18
// 124.213 us; speedup vs baseline: 1.6161x; 1.6161x over previous
//
#include <hip/hip_runtime.h>

#define L_SEQ 2048
#define NH    16
#define E_DIM 1024
#define M_ROWS 4096

typedef unsigned short u16;
typedef unsigned int   u32;
typedef __attribute__((ext_vector_type(8))) __bf16 bf16x8;
typedef __attribute__((ext_vector_type(4))) float  f32x4;

__device__ __forceinline__ u16 f2bf(float f) {
  union { float f; u32 u; } x; x.f = f;
  u32 u = x.u;
  return (u16)((u + 0x7FFFu + ((u >> 16) & 1u)) >> 16);
}
__device__ __forceinline__ float bf2f(u16 v) {
  union { u32 u; float f; } x; x.u = ((u32)v) << 16;
  return x.f;
}
__device__ __forceinline__ void st_bf4(u16* p, float a, float b, float c, float d) {
  ushort4 u; u.x = f2bf(a); u.y = f2bf(b); u.z = f2bf(c); u.w = f2bf(d);
  *reinterpret_cast<ushort4*>(p) = u;
}
// async global->LDS, 16B per lane; LDS dest must be linear in lane order
__device__ __forceinline__ void gload16(const u16* g, u16* l) {
  __builtin_amdgcn_global_load_lds(
      (const __attribute__((address_space(1))) void*)g,
      (__attribute__((address_space(3))) void*)l, 16, 0, 0);
}
#define SBAR() asm volatile("s_barrier" ::: "memory")

// ---------------- fused prologue: 4x weight-transpose+gamma-fold | bias-fold | LN x-hat ----------------
// grid 8320: [0,4096) transpose, [4096,4224) bias_fold, [4224,8320) ln rows
__global__ __launch_bounds__(256) void prep_kernel(
    const float* __restrict__ tokens,
    const float* __restrict__ W0, const float* __restrict__ W1,
    const float* __restrict__ W2, const float* __restrict__ W3,
    const float* __restrict__ g0, const float* __restrict__ g1,
    const float* __restrict__ g2, const float* __restrict__ g3,
    const float* __restrict__ lb0, const float* __restrict__ lb1,
    const float* __restrict__ lb2, const float* __restrict__ lb3,
    const float* __restrict__ bs0, const float* __restrict__ bs1,
    const float* __restrict__ bs2, const float* __restrict__ bs3,
    u16* __restrict__ T0, u16* __restrict__ T1, u16* __restrict__ T2, u16* __restrict__ T3,
    float* __restrict__ bfold, u16* __restrict__ xhat)
{
  __shared__ __align__(16) float shm[32 * 33];
  const int bid = blockIdx.x;
  const int t = threadIdx.x;

  if (bid < 4096) {                                 // ---- transpose + gamma fold ----
    const int z = bid >> 10, rem = bid & 1023;
    const float* W = (z == 0) ? W0 : (z == 1) ? W1 : (z == 2) ? W2 : W3;
    const float* g = (z == 0) ? g0 : (z == 1) ? g1 : (z == 2) ? g2 : g3;
    u16* T = (z == 0) ? T0 : (z == 1) ? T1 : (z == 2) ? T2 : T3;
    float (*tile)[33] = (float(*)[33])shm;
    const int tx = t & 31, ty = t >> 5;
    const int bx = (rem & 31) * 32, by = (rem >> 5) * 32;
    #pragma unroll
    for (int r = 0; r < 4; ++r) {
      const int e = by + ty + r * 8;
      tile[ty + r * 8][tx] = W[(size_t)e * E_DIM + bx + tx] * g[e];
    }
    __syncthreads();
    #pragma unroll
    for (int r = 0; r < 4; ++r)
      T[(size_t)(bx + ty + r * 8) * E_DIM + by + tx] = f2bf(tile[tx][ty + r * 8]);
  } else if (bid < 4224) {                          // ---- bias fold ----
    const int idx = bid - 4096;
    const int z = idx >> 5;
    const float* W  = (z == 0) ? W0 : (z == 1) ? W1 : (z == 2) ? W2 : W3;
    const float* bl = (z == 0) ? lb0 : (z == 1) ? lb1 : (z == 2) ? lb2 : lb3;
    const float* bs = (z == 0) ? bs0 : (z == 1) ? bs1 : (z == 2) ? bs2 : bs3;
    float (*part)[32] = (float(*)[32])shm;
    const int tn = t & 31, te = t >> 5;
    const int n = (idx & 31) * 32 + tn;
    float acc = 0.f;
    const int e0 = te * 128;
    for (int e = e0; e < e0 + 128; ++e) acc += bl[e] * W[(size_t)e * E_DIM + n];
    part[te][tn] = acc;
    __syncthreads();
    if (te == 0) {
      float s = part[0][tn] + part[1][tn] + part[2][tn] + part[3][tn]
              + part[4][tn] + part[5][tn] + part[6][tn] + part[7][tn];
      bfold[z * E_DIM + n] = bs[n] + s;
    }
  } else {                                          // ---- LN x-hat (fp32 in -> bf16 out) ----
    float* red = shm;
    const size_t row = bid - 4224;
    float4 v = reinterpret_cast<const float4*>(tokens + row * E_DIM)[t];
    float s = v.x + v.y + v.z + v.w;
    float q = v.x*v.x + v.y*v.y + v.z*v.z + v.w*v.w;
    #pragma unroll
    for (int off = 32; off; off >>= 1) { s += __shfl_down(s, off); q += __shfl_down(q, off); }
    if ((t & 63) == 0) { red[t >> 6] = s; red[4 + (t >> 6)] = q; }
    __syncthreads();
    float S = red[0] + red[1] + red[2] + red[3];
    float Q = red[4] + red[5] + red[6] + red[7];
    float mean = S * (1.f / E_DIM);
    float rstd = rsqrtf(Q * (1.f / E_DIM) - mean * mean + 1e-5f);
    st_bf4(xhat + row * E_DIM + t * 4,
           (v.x - mean) * rstd, (v.y - mean) * rstd, (v.z - mean) * rstd, (v.w - mean) * rstd);
  }
}

// ---------------- LayerNorm x-hat only: bf16 in -> bf16 out (fallback path) ----------------
__global__ __launch_bounds__(256) void ln_hat_bf16(const u16* __restrict__ x, u16* __restrict__ o)
{
  __shared__ float red[8];
  const size_t row = blockIdx.x;
  const int t = threadIdx.x;
  ushort4 u = reinterpret_cast<const ushort4*>(x + row * E_DIM)[t];
  float v0 = bf2f(u.x), v1 = bf2f(u.y), v2 = bf2f(u.z), v3 = bf2f(u.w);
  float s = v0 + v1 + v2 + v3;
  float q = v0*v0 + v1*v1 + v2*v2 + v3*v3;
  #pragma unroll
  for (int off = 32; off; off >>= 1) { s += __shfl_down(s, off); q += __shfl_down(q, off); }
  if ((t & 63) == 0) { red[t >> 6] = s; red[4 + (t >> 6)] = q; }
  __syncthreads();
  float S = red[0] + red[1] + red[2] + red[3];
  float Q = red[4] + red[5] + red[6] + red[7];
  float mean = S * (1.f / E_DIM);
  float rstd = rsqrtf(Q * (1.f / E_DIM) - mean * mean + 1e-5f);
  st_bf4(o + row * E_DIM + t * 4,
         (v0 - mean) * rstd, (v1 - mean) * rstd, (v2 - mean) * rstd, (v3 - mean) * rstd);
}

// ---------------- combine(A-tile partials) + LayerNorm x-hat, one row per block ----------------
// Rows with qt>=16 come from po/pml partials (combined inline); qt<=15 rows read wvb.
__global__ __launch_bounds__(256) void ln_combine_hat(
    const u16* __restrict__ wvb, const float* __restrict__ po,
    const float* __restrict__ pml, u16* __restrict__ what)
{
  __shared__ float red[8];
  const int row = blockIdx.x;                       // b*L_SEQ + l
  const int t = threadIdx.x;
  const int l = row & (L_SEQ - 1), b = row >> 11;
  const int qt = l >> 6;
  float v0, v1, v2, v3;
  if (qt >= 16) {
    const int pr = 31 - qt;
    const int c = t * 4;
    const int h = c >> 6, d0 = c & 63;
    const int bh = b * NH + h;
    const int base = (bh * 16 + pr) * 2;
    const int rr = l & 63;
    const float m0 = pml[(size_t)base * 128 + rr];
    const float s0 = pml[(size_t)base * 128 + 64 + rr];
    const float m1 = pml[(size_t)(base + 1) * 128 + rr];
    const float s1 = pml[(size_t)(base + 1) * 128 + 64 + rr];
    const float mm = fmaxf(m0, m1);
    const float a0 = __expf(m0 - mm), a1 = __expf(m1 - mm);
    const float inv = 1.f / (s0 * a0 + s1 * a1);
    float4 x0 = *reinterpret_cast<const float4*>(po + ((size_t)base * 64 + rr) * 64 + d0);
    float4 x1 = *reinterpret_cast<const float4*>(po + ((size_t)(base + 1) * 64 + rr) * 64 + d0);
    v0 = (x0.x * a0 + x1.x * a1) * inv;
    v1 = (x0.y * a0 + x1.y * a1) * inv;
    v2 = (x0.z * a0 + x1.z * a1) * inv;
    v3 = (x0.w * a0 + x1.w * a1) * inv;
  } else {
    ushort4 u = reinterpret_cast<const ushort4*>(wvb + (size_t)row * E_DIM)[t];
    v0 = bf2f(u.x); v1 = bf2f(u.y); v2 = bf2f(u.z); v3 = bf2f(u.w);
  }
  float s = v0 + v1 + v2 + v3;
  float q = v0*v0 + v1*v1 + v2*v2 + v3*v3;
  #pragma unroll
  for (int off = 32; off; off >>= 1) { s += __shfl_down(s, off); q += __shfl_down(q, off); }
  if ((t & 63) == 0) { red[t >> 6] = s; red[4 + (t >> 6)] = q; }
  __syncthreads();
  float S = red[0] + red[1] + red[2] + red[3];
  float Q = red[4] + red[5] + red[6] + red[7];
  float mean = S * (1.f / E_DIM);
  float rstd = rsqrtf(Q * (1.f / E_DIM) - mean * mean + 1e-5f);
  st_bf4(what + (size_t)row * E_DIM + t * 4,
         (v0 - mean) * rstd, (v1 - mean) * rstd, (v2 - mean) * rstd, (v3 - mean) * rstd);
}

// ---------------- 128x128 counted-vmcnt GEMM core, BK=64, 4 waves, 64 KB LDS (R8-proven) ----------------
#define GBK 64
__device__ __forceinline__ void core128(
    const u16* __restrict__ A, const u16* __restrict__ BT,
    int m0, int n0, int t, u16* lds, f32x4 (&acc)[4][4])
{
  const int lane = t & 63, wave = t >> 6;
  const int wm = wave >> 1, wn = wave & 1;
  const int fr = lane & 15, hi = lane >> 4;
  const int sx = fr & 7;

  auto STAGE = [&](int buf, int kt) {
    u16* la = lds + (buf * 2 + 0) * (128 * GBK);
    u16* lb = lds + (buf * 2 + 1) * (128 * GBK);
    #pragma unroll
    for (int s = 0; s < 4; ++s) {
      const int seg = t + s * 256;
      const int r = seg >> 3;
      const int gc = (seg & 7) ^ (r & 7);            // inverse-swizzled source chunk
      gload16(A + (size_t)(m0 + r) * E_DIM + kt * GBK + gc * 8, la + seg * 8);
    }
    #pragma unroll
    for (int s = 0; s < 4; ++s) {
      const int seg = t + s * 256;
      const int r = seg >> 3;
      const int gc = (seg & 7) ^ (r & 7);
      gload16(BT + (size_t)(n0 + r) * E_DIM + kt * GBK + gc * 8, lb + seg * 8);
    }
  };
  auto AF = [&](int buf, int i, int ks) -> bf16x8 {
    return *reinterpret_cast<const bf16x8*>(
        lds + (buf * 2 + 0) * (128 * GBK) + (wm * 64 + i * 16 + fr) * GBK + (((ks * 4 + hi) ^ sx) * 8));
  };
  auto BF = [&](int buf, int j, int ks) -> bf16x8 {
    return *reinterpret_cast<const bf16x8*>(
        lds + (buf * 2 + 1) * (128 * GBK) + (wn * 64 + j * 16 + fr) * GBK + (((ks * 4 + hi) ^ sx) * 8));
  };
  auto PHASES = [&](int buf) {
    bf16x8 a[4][2], b[4][2];
    #pragma unroll
    for (int i = 0; i < 4; ++i) { a[i][0] = AF(buf, i, 0); a[i][1] = AF(buf, i, 1); }
    #pragma unroll
    for (int j = 0; j < 4; ++j) { b[j][0] = BF(buf, j, 0); b[j][1] = BF(buf, j, 1); }
    __builtin_amdgcn_s_setprio(1);
    #pragma unroll
    for (int i = 0; i < 4; ++i)
      #pragma unroll
      for (int j = 0; j < 4; ++j) {
        acc[i][j] = __builtin_amdgcn_mfma_f32_16x16x32_bf16(a[i][0], b[j][0], acc[i][j], 0, 0, 0);
        acc[i][j] = __builtin_amdgcn_mfma_f32_16x16x32_bf16(a[i][1], b[j][1], acc[i][j], 0, 0, 0);
      }
    __builtin_amdgcn_s_setprio(0);
  };

  STAGE(0, 0);                                      // prologue: kt0's 8 loads in flight
  #pragma unroll 1
  for (int kt = 0; kt < 15; ++kt) {
    const int buf = kt & 1;
    SBAR();                                         // all waves done reading buf^1 (kt-1)
    STAGE(buf ^ 1, kt + 1);                         // kt+1's 8 loads: stay in flight
    asm volatile("s_waitcnt vmcnt(8)" ::: "memory");// own kt loads done
    SBAR();                                         // => ALL waves' kt loads landed
    PHASES(buf);
  }
  asm volatile("s_waitcnt vmcnt(0)" ::: "memory");  // peeled last K-tile (kt=15, buf=1)
  SBAR();
  PHASES(1);
}

// ---------------- fused QKV GEMM: 768 blocks (32m x 24n), z = n0>>10 ----------------
// XCD-rectangle mapping (8m x 12n per XCD). Epilogue: scattered column-major stores
// (z=1 kout fp32, z=2 vTb bf16) go through an LDS transpose -> coalesced runs along L.
__global__ __launch_bounds__(256, 2) void gemm_qkv128(
    const u16* __restrict__ xhat, const u16* __restrict__ WTcat,
    const float* __restrict__ bfold,
    float* __restrict__ kout, float* __restrict__ vout,
    u16* __restrict__ qbf, u16* __restrict__ kbf, u16* __restrict__ vTb)
{
  __shared__ __align__(16) char smraw[128 * 132 * 4];   // 67.5 KB: core (64KB) / f32 xp[128][132] / u32 vp[128][68]
  u16* lds = (u16*)smraw;
  const int t = threadIdx.x;
  const int xcd = blockIdx.x & 7, l = blockIdx.x >> 3;  // l in [0,96)
  const int by = 8 * (xcd >> 1) + l / 12;
  const int bx = 12 * (xcd & 1) + l % 12;
  const int m0 = by * 128, n0 = bx * 128;

  f32x4 acc[4][4] = {};
  core128(xhat, WTcat, m0, n0, t, lds, acc);

  const int lane = t & 63, wave = t >> 6;
  const int wm = wave >> 1, wn = wave & 1;
  const int fr = lane & 15, hi = lane >> 4;
  const int z = n0 >> 10;
  const float* bias = bfold + z * E_DIM;
  const int rowb = hi * 4;
  const int bb = m0 >> 11;                              // batch (tile never crosses)

  if (z == 0) {
    #pragma unroll
    for (int i = 0; i < 4; ++i) {
      const int mbase = m0 + wm * 64 + i * 16 + rowb;
      #pragma unroll
      for (int j = 0; j < 4; ++j) {
        const int ncol = (n0 + wn * 64 + j * 16 + fr) & 1023;
        const float bval = bias[ncol];
        const int h = ncol >> 6, d = ncol & 63;
        #pragma unroll
        for (int r = 0; r < 4; ++r) {
          const int m = mbase + r;
          const int ltok = m & 2047;
          qbf[(((size_t)(bb * NH + h) * L_SEQ + ltok) << 6) + d] = f2bf(acc[i][j][r] + bval);
        }
      }
    }
  } else if (z == 1) {
    // kbf (row-major) direct; kout (fp32 column-major) via LDS transpose
    __syncthreads();                                    // core done with lds
    float (*xp)[132] = (float(*)[132])smraw;
    #pragma unroll
    for (int i = 0; i < 4; ++i) {
      const int mbase = m0 + wm * 64 + i * 16 + rowb;
      const int mloc = wm * 64 + i * 16 + rowb;
      #pragma unroll
      for (int j = 0; j < 4; ++j) {
        const int nl = wn * 64 + j * 16 + fr;
        const int ncol = (n0 + nl) & 1023;
        const float bval = bias[ncol];
        const int h = ncol >> 6, d = ncol & 63;
        #pragma unroll
        for (int r = 0; r < 4; ++r) {
          const int m = mbase + r;
          const int ltok = m & 2047;
          const float val = acc[i][j][r] + bval;
          kbf[(((size_t)(bb * NH + h) * L_SEQ + ltok) << 6) + d] = f2bf(val);
          xp[nl][mloc + r] = val;
        }
      }
    }
    __syncthreads();
    const int nl = t >> 1, mh = (t & 1) * 64;
    const int ncol2 = (n0 + nl) & 1023;
    const int h2 = ncol2 >> 6, d2 = ncol2 & 63;
    float4* dst = (float4*)(kout + ((size_t)(bb * NH + h2) * 64 + d2) * L_SEQ + (m0 & 2047) + mh);
    #pragma unroll
    for (int u = 0; u < 16; ++u)
      dst[u] = *reinterpret_cast<float4*>(&xp[nl][mh + u * 4]);
  } else {
    // vout (row-major-ish) direct; vTb (bf16 column-major) via LDS transpose (u32-packed)
    __syncthreads();
    u32 (*vp)[68] = (u32(*)[68])smraw;
    #pragma unroll
    for (int i = 0; i < 4; ++i) {
      const int mbase = m0 + wm * 64 + i * 16 + rowb;
      const int mloc = wm * 64 + i * 16 + rowb;
      #pragma unroll
      for (int j = 0; j < 4; ++j) {
        const int nl = wn * 64 + j * 16 + fr;
        const int ncol = (n0 + nl) & 1023;
        const float bval = bias[ncol];
        const int h = ncol >> 6, d = ncol & 63;
        float v4[4];
        #pragma unroll
        for (int r = 0; r < 4; ++r) {
          const int m = mbase + r;
          const int ltok = m & 2047;
          v4[r] = acc[i][j][r] + bval;
          vout[((size_t)(bb * NH + h) * L_SEQ + ltok) * 64 + d] = v4[r];
        }
        vp[nl][(mloc >> 1) + 0] = (u32)f2bf(v4[0]) | ((u32)f2bf(v4[1]) << 16);
        vp[nl][(mloc >> 1) + 1] = (u32)f2bf(v4[2]) | ((u32)f2bf(v4[3]) << 16);
      }
    }
    __syncthreads();
    const int nl = t >> 1, mh = (t & 1) * 64;
    const int ncol2 = (n0 + nl) & 1023;
    const int h2 = ncol2 >> 6, d2 = ncol2 & 63;
    uint4* dst = (uint4*)(vTb + ((size_t)(bb * NH + h2) * 64 + d2) * L_SEQ + (m0 & 2047) + mh);
    #pragma unroll
    for (int u = 0; u < 8; ++u)
      dst[u] = *reinterpret_cast<uint4*>(&vp[nl][(mh >> 1) + u * 4]);
  }
}

// ---------------- final GEMM: out = what @ (g_o . Wo) + bfold_o + tokens; 256 blocks ----------------
__global__ __launch_bounds__(256, 2) void gemm_o128(
    const u16* __restrict__ A, const u16* __restrict__ BT, const float* __restrict__ bias,
    const float* __restrict__ tokens, float* __restrict__ out)
{
  __shared__ u16 lds[4 * 128 * GBK];
  const int t = threadIdx.x;
  const int xcd = blockIdx.x & 7, l = blockIdx.x >> 3;  // l in [0,32)
  const int by = 8 * (xcd >> 1) + (l >> 2);
  const int bx = 4 * (xcd & 1) + (l & 3);
  const int m0 = by * 128, n0 = bx * 128;

  f32x4 acc[4][4] = {};
  core128(A, BT, m0, n0, t, lds, acc);

  const int lane = t & 63, wave = t >> 6;
  const int wm = wave >> 1, wn = wave & 1;
  const int fr = lane & 15, hi = lane >> 4;
  const int rowb = hi * 4;
  #pragma unroll
  for (int i = 0; i < 4; ++i) {
    const int mbase = m0 + wm * 64 + i * 16 + rowb;
    #pragma unroll
    for (int j = 0; j < 4; ++j) {
      const int ncol = n0 + wn * 64 + j * 16 + fr;
      const float bval = bias[ncol];
      #pragma unroll
      for (int r = 0; r < 4; ++r) {
        const int m = mbase + r;
        out[(size_t)m * E_DIM + ncol] = acc[i][j][r] + bval + tokens[(size_t)m * E_DIM + ncol];
      }
    }
  }
}

// ---------------- MFMA flash attention, SPLIT-PAIR (4 blocks/CU) — R15-proven ----------------
__global__ __launch_bounds__(256, 4) void attn_split(
    const u16* __restrict__ qbf, const u16* __restrict__ kbf,
    const u16* __restrict__ vTb, u16* __restrict__ wv,
    float* __restrict__ po, float* __restrict__ pml)
{
  __shared__ u16 Klds[64][72];
  __shared__ u16 Vlds[64][72];
  __shared__ u16 Plds[4][16][72];
  const int t = threadIdx.x, lane = t & 63, wave = t >> 6;
  const int bi = blockIdx.x;
  const int bh = (bi & 7) + 8 * ((bi >> 3) & 3);   // b*NH + h, XCD-grouped
  const int pp = bi >> 5;                          // 0..31
  const int half = pp & 1, pr = pp >> 1;           // pair 0..15
  const int fr = lane & 15, hi = lane >> 4;
  const u16* kbase = kbf + (size_t)bh * L_SEQ * 64;
  const u16* vbase = vTb + (size_t)bh * 64 * L_SEQ;
  const int b = bh >> 4, h = bh & 15;
  const int qtA = 31 - pr, qtB = pr;

  auto STG = [&](int j0) {
    #pragma unroll
    for (int s = 0; s < 2; ++s) {
      const int seg = t + s * 256;
      const int r = seg >> 3, c8 = (seg & 7) * 8;
      *reinterpret_cast<uint4*>(&Klds[r][c8]) =
          *reinterpret_cast<const uint4*>(kbase + (size_t)(j0 + r) * 64 + c8);
      *reinterpret_cast<uint4*>(&Vlds[r][c8]) =
          *reinterpret_cast<const uint4*>(vbase + (size_t)r * L_SEQ + j0 + c8);
    }
  };
  auto TILE = [&](const bf16x8& qf0, const bf16x8& qf1, int qg, bool diag, int j0,
                  f32x4 (&o)[4], float& mrun, float& lrun) {
    f32x4 st[4] = {};
    __builtin_amdgcn_s_setprio(1);
    #pragma unroll
    for (int kt = 0; kt < 4; ++kt) {
      bf16x8 ka0 = *reinterpret_cast<const bf16x8*>(&Klds[kt*16 + fr][hi*8]);
      bf16x8 ka1 = *reinterpret_cast<const bf16x8*>(&Klds[kt*16 + fr][32 + hi*8]);
      st[kt] = __builtin_amdgcn_mfma_f32_16x16x32_bf16(ka0, qf0, st[kt], 0, 0, 0);
      st[kt] = __builtin_amdgcn_mfma_f32_16x16x32_bf16(ka1, qf1, st[kt], 0, 0, 0);
    }
    __builtin_amdgcn_s_setprio(0);

    float p[16];
    float pmax = -3.0e38f;
    #pragma unroll
    for (int kt = 0; kt < 4; ++kt)
      #pragma unroll
      for (int r = 0; r < 4; ++r) {
        const int key = j0 + kt*16 + hi*4 + r;
        const float v = st[kt][r] * 0.125f + ((diag && key > qg) ? -1249.875f : 0.f);
        p[kt*4 + r] = v;
        pmax = fmaxf(pmax, v);
      }
    pmax = fmaxf(pmax, __shfl_xor(pmax, 16));
    pmax = fmaxf(pmax, __shfl_xor(pmax, 32));
    const float mnew = fmaxf(mrun, pmax);
    const float alpha = __expf(mrun - mnew);
    float lsum = 0.f;
    #pragma unroll
    for (int i = 0; i < 16; ++i) { p[i] = __expf(p[i] - mnew); lsum += p[i]; }
    lsum += __shfl_xor(lsum, 16);
    lsum += __shfl_xor(lsum, 32);
    lrun = lrun * alpha + lsum;
    mrun = mnew;
    #pragma unroll
    for (int r = 0; r < 4; ++r) {
      const float ar = __shfl(alpha, hi*4 + r);
      o[0][r] *= ar; o[1][r] *= ar; o[2][r] *= ar; o[3][r] *= ar;
    }
    #pragma unroll
    for (int kt = 0; kt < 4; ++kt) {
      ushort4 w4;
      w4.x = f2bf(p[kt*4+0]); w4.y = f2bf(p[kt*4+1]);
      w4.z = f2bf(p[kt*4+2]); w4.w = f2bf(p[kt*4+3]);
      *reinterpret_cast<ushort4*>(&Plds[wave][fr][kt*16 + hi*4]) = w4;
    }
    const bf16x8 pf0 = *reinterpret_cast<const bf16x8*>(&Plds[wave][fr][hi*8]);
    const bf16x8 pf1 = *reinterpret_cast<const bf16x8*>(&Plds[wave][fr][32 + hi*8]);
    __builtin_amdgcn_s_setprio(1);
    #pragma unroll
    for (int dt = 0; dt < 4; ++dt) {
      bf16x8 vf0 = *reinterpret_cast<const bf16x8*>(&Vlds[dt*16 + fr][hi*8]);
      bf16x8 vf1 = *reinterpret_cast<const bf16x8*>(&Vlds[dt*16 + fr][32 + hi*8]);
      o[dt] = __builtin_amdgcn_mfma_f32_16x16x32_bf16(pf0, vf0, o[dt], 0, 0, 0);
      o[dt] = __builtin_amdgcn_mfma_f32_16x16x32_bf16(pf1, vf1, o[dt], 0, 0, 0);
    }
    __builtin_amdgcn_s_setprio(0);
  };

  // ---- tile A segment ----
  {
    const int q0w = qtA * 64 + wave * 16;
    const int qg = q0w + fr;
    const u16* qrow = qbf + ((size_t)bh * L_SEQ + q0w + fr) * 64 + hi * 8;
    const bf16x8 qf0 = *reinterpret_cast<const bf16x8*>(qrow);
    const bf16x8 qf1 = *reinterpret_cast<const bf16x8*>(qrow + 32);
    f32x4 o[4] = {};
    float mrun = -3.0e38f, lrun = 0.f;
    const int lo = half ? 17 : 0;
    const int hiT = half ? qtA : 16;               // qtA >= 16 always; empty when half=1 && pr=15
    #pragma unroll 1
    for (int tkv = lo; tkv <= hiT; ++tkv) {
      STG(tkv * 64);
      __syncthreads();
      TILE(qf0, qf1, qg, tkv == qtA, tkv * 64, o, mrun, lrun);
      __syncthreads();
    }
    const int slot = (bh * 16 + pr) * 2 + half;
    float* pob = po + (size_t)slot * 4096;
    #pragma unroll
    for (int dt = 0; dt < 4; ++dt)
      #pragma unroll
      for (int r = 0; r < 4; ++r)
        pob[(wave * 16 + hi * 4 + r) * 64 + dt * 16 + fr] = o[dt][r];
    if (hi == 0) {
      pml[slot * 128 + wave * 16 + fr] = mrun;
      pml[slot * 128 + 64 + wave * 16 + fr] = lrun;
    }
  }

  // ---- tile B (half1 only, full range, written directly) ----
  if (half) {
    const int q0w = qtB * 64 + wave * 16;
    const int qg = q0w + fr;
    const u16* qrow = qbf + ((size_t)bh * L_SEQ + q0w + fr) * 64 + hi * 8;
    const bf16x8 qf0 = *reinterpret_cast<const bf16x8*>(qrow);
    const bf16x8 qf1 = *reinterpret_cast<const bf16x8*>(qrow + 32);
    f32x4 o[4] = {};
    float mrun = -3.0e38f, lrun = 0.f;
    #pragma unroll 1
    for (int tkv = 0; tkv <= qtB; ++tkv) {
      __syncthreads();                              // previous reads (incl. tile-A loop) done
      STG(tkv * 64);
      __syncthreads();
      TILE(qf0, qf1, qg, tkv == qtB, tkv * 64, o, mrun, lrun);
    }
    const float inv = 1.f / lrun;
    #pragma unroll
    for (int r = 0; r < 4; ++r) {
      const float ir = __shfl(inv, hi * 4 + r);
      const int q = q0w + hi * 4 + r;
      u16* dst = wv + (size_t)(b * L_SEQ + q) * E_DIM + h * 64 + fr;
      #pragma unroll
      for (int dt = 0; dt < 4; ++dt)
        dst[dt * 16] = f2bf(o[dt][r] * ir);
    }
  }
}

// ---------------- combine tile-A partials (fallback only) ----------------
__global__ __launch_bounds__(256) void attn_combine(
    const float* __restrict__ po, const float* __restrict__ pml, u16* __restrict__ wv)
{
  const int pair = blockIdx.x;                     // bh*16 + pr
  const int bh = pair >> 4, pr = pair & 15;
  const int b = bh >> 4, h = bh & 15;
  const int q0 = (31 - pr) * 64;
  const int t = threadIdx.x;
  const int r = t >> 2, c0 = (t & 3) * 16;
  const float m0 = pml[(size_t)(pair * 2 + 0) * 128 + r];
  const float l0 = pml[(size_t)(pair * 2 + 0) * 128 + 64 + r];
  const float m1 = pml[(size_t)(pair * 2 + 1) * 128 + r];
  const float l1 = pml[(size_t)(pair * 2 + 1) * 128 + 64 + r];
  const float mm = fmaxf(m0, m1);
  const float a0 = __expf(m0 - mm), a1 = __expf(m1 - mm);
  const float inv = 1.f / (l0 * a0 + l1 * a1);
  const float* o0 = po + ((size_t)(pair * 2 + 0) * 64 + r) * 64 + c0;
  const float* o1 = po + ((size_t)(pair * 2 + 1) * 64 + r) * 64 + c0;
  u16* dst = wv + (size_t)(b * L_SEQ + q0 + r) * E_DIM + h * 64 + c0;
  #pragma unroll
  for (int c = 0; c < 16; c += 4) {
    float4 x0 = *reinterpret_cast<const float4*>(o0 + c);
    float4 x1 = *reinterpret_cast<const float4*>(o1 + c);
    st_bf4(dst + c,
           (x0.x * a0 + x1.x * a1) * inv, (x0.y * a0 + x1.y * a1) * inv,
           (x0.z * a0 + x1.z * a1) * inv, (x0.w * a0 + x1.w * a1) * inv);
  }
}

// ---------------- MFMA flash attention, q-tile-paired — R8-proven fallback ----------------
__global__ __launch_bounds__(256) void attn_mfma(
    const u16* __restrict__ qbf, const u16* __restrict__ kbf,
    const u16* __restrict__ vTb, u16* __restrict__ wv)
{
  __shared__ u16 Klds[64][72];
  __shared__ u16 Vlds[64][72];
  __shared__ u16 Plds[4][16][72];
  const int t = threadIdx.x, lane = t & 63, wave = t >> 6;
  const int bi = blockIdx.x;
  const int bh = (bi & 7) + 8 * ((bi >> 3) & 3);
  const int pr = bi >> 5;
  const int fr = lane & 15, hi = lane >> 4;
  const u16* kbase = kbf + (size_t)bh * L_SEQ * 64;
  const u16* vbase = vTb + (size_t)bh * 64 * L_SEQ;
  const int b = bh >> 4, h = bh & 15;

  #pragma unroll 1
  for (int half = 0; half < 2; ++half) {
    const int qt = half ? (31 - pr) : pr;
    const int q0w = qt * 64 + wave * 16;
    const int qg = q0w + fr;
    const u16* qrow = qbf + ((size_t)bh * L_SEQ + q0w + fr) * 64 + hi * 8;
    const bf16x8 qf0 = *reinterpret_cast<const bf16x8*>(qrow);
    const bf16x8 qf1 = *reinterpret_cast<const bf16x8*>(qrow + 32);
    f32x4 o[4] = {};
    float mrun = -3.0e38f, lrun = 0.f;

    for (int tkv = 0; tkv <= qt; ++tkv) {
      const int j0 = tkv * 64;
      const bool diag = (tkv == qt);
      #pragma unroll
      for (int s = 0; s < 2; ++s) {
        const int seg = t + s * 256;
        const int r = seg >> 3, c8 = (seg & 7) * 8;
        *reinterpret_cast<uint4*>(&Klds[r][c8]) =
            *reinterpret_cast<const uint4*>(kbase + (size_t)(j0 + r) * 64 + c8);
        *reinterpret_cast<uint4*>(&Vlds[r][c8]) =
            *reinterpret_cast<const uint4*>(vbase + (size_t)r * L_SEQ + j0 + c8);
      }
      __syncthreads();

      f32x4 st[4] = {};
      __builtin_amdgcn_s_setprio(1);
      #pragma unroll
      for (int kt = 0; kt < 4; ++kt) {
        bf16x8 ka0 = *reinterpret_cast<const bf16x8*>(&Klds[kt*16 + fr][hi*8]);
        bf16x8 ka1 = *reinterpret_cast<const bf16x8*>(&Klds[kt*16 + fr][32 + hi*8]);
        st[kt] = __builtin_amdgcn_mfma_f32_16x16x32_bf16(ka0, qf0, st[kt], 0, 0, 0);
        st[kt] = __builtin_amdgcn_mfma_f32_16x16x32_bf16(ka1, qf1, st[kt], 0, 0, 0);
      }
      __builtin_amdgcn_s_setprio(0);

      float p[16];
      float pmax = -3.0e38f;
      #pragma unroll
      for (int kt = 0; kt < 4; ++kt)
        #pragma unroll
        for (int r = 0; r < 4; ++r) {
          const int key = j0 + kt*16 + hi*4 + r;
          const float v = st[kt][r] * 0.125f + ((diag && key > qg) ? -1249.875f : 0.f);
          p[kt*4 + r] = v;
          pmax = fmaxf(pmax, v);
        }
      pmax = fmaxf(pmax, __shfl_xor(pmax, 16));
      pmax = fmaxf(pmax, __shfl_xor(pmax, 32));
      const float mnew = fmaxf(mrun, pmax);
      const float alpha = __expf(mrun - mnew);
      float lsum = 0.f;
      #pragma unroll
      for (int i = 0; i < 16; ++i) { p[i] = __expf(p[i] - mnew); lsum += p[i]; }
      lsum += __shfl_xor(lsum, 16);
      lsum += __shfl_xor(lsum, 32);
      lrun = lrun * alpha + lsum;
      mrun = mnew;
      #pragma unroll
      for (int r = 0; r < 4; ++r) {
        const float ar = __shfl(alpha, hi*4 + r);
        o[0][r] *= ar; o[1][r] *= ar; o[2][r] *= ar; o[3][r] *= ar;
      }
      #pragma unroll
      for (int kt = 0; kt < 4; ++kt) {
        ushort4 w4;
        w4.x = f2bf(p[kt*4+0]); w4.y = f2bf(p[kt*4+1]);
        w4.z = f2bf(p[kt*4+2]); w4.w = f2bf(p[kt*4+3]);
        *reinterpret_cast<ushort4*>(&Plds[wave][fr][kt*16 + hi*4]) = w4;
      }
      const bf16x8 pf0 = *reinterpret_cast<const bf16x8*>(&Plds[wave][fr][hi*8]);
      const bf16x8 pf1 = *reinterpret_cast<const bf16x8*>(&Plds[wave][fr][32 + hi*8]);
      __builtin_amdgcn_s_setprio(1);
      #pragma unroll
      for (int dt = 0; dt < 4; ++dt) {
        bf16x8 vf0 = *reinterpret_cast<const bf16x8*>(&Vlds[dt*16 + fr][hi*8]);
        bf16x8 vf1 = *reinterpret_cast<const bf16x8*>(&Vlds[dt*16 + fr][32 + hi*8]);
        o[dt] = __builtin_amdgcn_mfma_f32_16x16x32_bf16(pf0, vf0, o[dt], 0, 0, 0);
        o[dt] = __builtin_amdgcn_mfma_f32_16x16x32_bf16(pf1, vf1, o[dt], 0, 0, 0);
      }
      __builtin_amdgcn_s_setprio(0);
      __syncthreads();
    }

    const float inv = 1.f / lrun;
    #pragma unroll
    for (int r = 0; r < 4; ++r) {
      const float ir = __shfl(inv, hi*4 + r);
      const int q = q0w + hi*4 + r;
      u16* dst = wv + (size_t)(b * L_SEQ + q) * E_DIM + h * 64 + fr;
      #pragma unroll
      for (int dt = 0; dt < 4; ++dt)
        dst[dt * 16] = f2bf(o[dt][r] * ir);
    }
  }
}

extern "C" void kernel_launch(void* const* d_in, const int* in_sizes, int n_in,
                              void* d_out, int out_size, void* d_ws, size_t ws_size,
                              hipStream_t stream) {
  (void)in_sizes; (void)n_in; (void)out_size;
  const float* tokens = (const float*)d_in[0];
  const float* ln_q_g = (const float*)d_in[1];
  const float* ln_q_b = (const float*)d_in[2];
  const float* Wq     = (const float*)d_in[3];
  const float* bq     = (const float*)d_in[4];
  const float* ln_k_g = (const float*)d_in[5];
  const float* ln_k_b = (const float*)d_in[6];
  const float* Wk     = (const float*)d_in[7];
  const float* bk     = (const float*)d_in[8];
  const float* ln_v_g = (const float*)d_in[9];
  const float* ln_v_b = (const float*)d_in[10];
  const float* Wv     = (const float*)d_in[11];
  const float* bv     = (const float*)d_in[12];
  const float* ln_o_g = (const float*)d_in[13];
  const float* ln_o_b = (const float*)d_in[14];
  const float* Wo     = (const float*)d_in[15];
  const float* bo     = (const float*)d_in[16];

  float* out  = (float*)d_out;            // (2,2048,1024)
  float* kout = out + 4194304;            // (2,16,64,2048)
  float* vout = kout + 4194304;           // (2,16,2048,64)

  char* w = (char*)d_ws;
  const size_t MB = (size_t)1 << 20;
  u16*   WTq   = (u16*)(w + 0 * MB);     // (g_q . Wq)^T — WTq/WTv/WTk contiguous = WTcat (3072 x 1024)
  u16*   WTv   = (u16*)(w + 2 * MB);
  u16*   WTk   = (u16*)(w + 4 * MB);
  u16*   WTo   = (u16*)(w + 6 * MB);     // (g_o . Wo)^T
  u16*   xhat  = (u16*)(w + 8 * MB);     // shared LN x-hat; REUSED as wvb after gemm_qkv
  u16*   qbf   = (u16*)(w + 16 * MB);    // q bf16 (N,H,L,64)
  u16*   kbf   = (u16*)(w + 24 * MB);    // k bf16 (N,H,L,64)
  u16*   vTb   = (u16*)(w + 32 * MB);    // v^T bf16 (N,H,64,L)
  u16*   what  = (u16*)(w + 40 * MB);    // LN x-hat of wv
  float* bfold = (float*)(w + 48 * MB);  // 4 x 1024 folded biases (q, k(Wv), v(Wk), o)
  float* po    = (float*)(w + 49 * MB);  // tile-A partial o: 1024 x 64 x 64 f32 (16 MB)
  float* pml   = (float*)(w + 65 * MB);  // tile-A partial m,l: 1024 x 128 f32 (512 KB)
  u16*   wvb   = xhat;                   // attn out (N,L,E) — xhat dead after gemm_qkv

  prep_kernel<<<8320, 256, 0, stream>>>(
      tokens,
      Wq, Wv, Wk, Wo,
      ln_q_g, ln_v_g, ln_k_g, ln_o_g,
      ln_q_b, ln_v_b, ln_k_b, ln_o_b,
      bq, bv, bk, bo,
      WTq, WTv, WTk, WTo, bfold, xhat);
  gemm_qkv128<<<768, 256, 0, stream>>>(xhat, WTq, bfold, kout, vout, qbf, kbf, vTb);
  if (ws_size >= 66 * MB) {
    attn_split<<<1024, 256, 0, stream>>>(qbf, kbf, vTb, wvb, po, pml);
    ln_combine_hat<<<M_ROWS, 256, 0, stream>>>(wvb, po, pml, what);
  } else {
    attn_mfma<<<512, 256, 0, stream>>>(qbf, kbf, vTb, wvb);
    ln_hat_bf16<<<M_ROWS, 256, 0, stream>>>(wvb, what);
  }
  gemm_o128<<<256, 256, 0, stream>>>(what, WTo, bfold + 3 * E_DIM, tokens, out);
}